// Round 8
// baseline (232.523 us; speedup 1.0000x reference)
//
#include <hip/hip_runtime.h>
#include <math.h>

#define B_      16
#define K_      200000
#define N_      40
#define TPB     256
#define ITEMS   8
#define TILE    (TPB * ITEMS)                 // 2048 elements per block
#define NBX     ((K_ + TILE - 1) / TILE)      // 98
#define NBLOCKS (NBX * B_)                    // 1568
#define NE      (2 * N_)                      // 80 endpoints
#define NACC    7

// ws: per-block partials only (NBLOCKS x 7 doubles = 87,808 B)

__global__ __launch_bounds__(TPB, 8) void msl_main(
    const float* __restrict__ loc,     // (B,K,2)
    const float* __restrict__ conf,    // (B,K,2)
    const float* __restrict__ ploc,    // (B,K,2)
    const float* __restrict__ pconf,   // (B,K,2)
    const float* __restrict__ center,  // (B,K,1)
    const float* __restrict__ priors,  // (K,1)
    const float* __restrict__ targets, // (B,N,3)
    double* __restrict__ partials)
{
    __shared__ float  tl0[N_], tr0[N_], lb0[N_], ar0[N_];
    __shared__ float  stl[N_], str[N_], slb[N_];
    __shared__ float  s_bp[NE];
    __shared__ float4 s_at[NE];
    __shared__ float4 s_gap[NE + 1];
    __shared__ float  s_list[NE];
    __shared__ int    s_bm[2];
    __shared__ double s_red[TPB / 64][NACC];

    const int b = blockIdx.y;
    const int t = threadIdx.x;
    const int kb = blockIdx.x * TILE;

    // ---- prologue: build this batch's match tables in LDS ----
    if (t < N_) {
        const float* tg = targets + (b * N_ + t) * 3;
        const float tl = tg[0], tr = tg[1];
        tl0[t] = tl; tr0[t] = tr; lb0[t] = tg[2];
        ar0[t] = (tr - tl) * 256.0f;
    }
    __syncthreads();

    // seg rank-sort by area (stable) -> priority order; endpoint rank-sort -> s_bp
    if (t < N_) {
        const float an = ar0[t];
        int r = 0;
        #pragma unroll
        for (int m = 0; m < N_; ++m) {
            const float am = ar0[m];
            r += (am < an) || (am == an && m < t);
        }
        stl[r] = tl0[t]; str[r] = tr0[t]; slb[r] = lb0[t];
    }
    if (t >= 128 && t < 128 + NE) {
        const int i = t - 128;
        const float v = (i < N_) ? tl0[i] : tr0[i - N_];
        int r = 0;
        #pragma unroll
        for (int m = 0; m < NE; ++m) {
            const float vm = (m < N_) ? tl0[m] : tr0[m - N_];
            r += (vm < v) || (vm == v && m < i);
        }
        s_bp[r] = v;
    }
    __syncthreads();

    // point winners (t<80), gap winners (t in [128,209)), breakpoint list (t==255)
    if (t < NE) {
        const float v = s_bp[t];
        int w = N_;
        for (int s = N_ - 1; s >= 0; --s)
            w = (stl[s] <= v && v <= str[s]) ? s : w;
        const bool ok = (w < N_);
        const int si = ok ? w : 0;
        s_at[t] = ok ? make_float4(stl[si], str[si], slb[si], 1.0f)
                     : make_float4(0.f, 0.f, 0.f, 0.f);
    }
    if (t >= 128 && t < 128 + NE + 1) {
        const int g = t - 128;                 // 0..80
        const float a  = g ? s_bp[g - 1] : -INFINITY;
        const float bb = (g < NE) ? s_bp[g] : INFINITY;
        int w = N_;
        for (int s = N_ - 1; s >= 0; --s)
            w = (stl[s] <= a && bb <= str[s]) ? s : w;
        const bool ok = (w < N_);
        const int si = ok ? w : 0;
        s_gap[g] = ok ? make_float4(stl[si], str[si], slb[si], 1.0f)
                      : make_float4(0.f, 0.f, 0.f, 0.f);
    }
    if (t == 255) {
        const int kend = (kb + TILE < K_) ? kb + TILE : K_;
        const float cmin = priors[kb];
        const float cmax = priors[kend - 1];
        int base = 0, m = 0;
        for (int i = 0; i < NE; ++i) {
            const float v = s_bp[i];
            base += (v < cmin) ? 1 : 0;
            if (v >= cmin && v <= cmax) s_list[m++] = v;
        }
        s_bm[0] = base; s_bm[1] = m;
    }
    __syncthreads();

    const int base = s_bm[0];
    const int m    = s_bm[1];

    const float EPS = 1.1920928955078125e-7f;  // FLT_EPSILON
    const int bK2 = b * K_ * 2;
    const int kbase = kb + t;

    float f0 = 0.f, f1 = 0.f, f2 = 0.f, f3 = 0.f, f4 = 0.f, f5 = 0.f, f6 = 0.f;

    auto body = [&](float c, float pl, float pr, float x0, float x1,
                    float p0, float p1, float y0, float y1, float lg) {
        // ---- match: pos = #bp <= c over tiny broadcast list ----
        int pos = base; bool eq = false;
        for (int jj = 0; jj < m; ++jj) {
            const float v = s_list[jj];          // wave-uniform broadcast
            pos += (v <= c) ? 1 : 0;
            eq  |= (v == c);
        }
        const float4 sg = eq ? s_at[pos - 1] : s_gap[pos];

        const float tl = sg.x, tr = sg.y;
        const int conf_t = (int)sg.z;            // 0 when unmatched
        const float lt0 = (c - tl) * 256.0f;
        const float lt1 = (tr - c) * 256.0f;

        const float inter = fminf(pl, lt0) + fminf(pr, lt1);
        const float uni   = pl + pr + (lt0 + lt1) - inter;
        const float iou   = __fdividef(inter, fmaxf(uni, EPS));
        const int pconf_t = (iou < 0.5f) ? 0 : conf_t;

        const float posf = (conf_t > 0) ? 1.0f : 0.0f;
        const float ppf  = (pconf_t > 0) ? 1.0f : 0.0f;

        // GIoU (pos only)
        const float ac   = fmaxf(pl, lt0) + fmaxf(pr, lt1);
        const float giou = iou - __fdividef(ac - uni, fmaxf(ac, EPS));
        f0 += (1.0f - giou) * posf;

        // prop loc L1 (prop-pos only)
        const float prop_w = pl + pr;
        const float rw = __fdividef(1.0f, 0.5f * prop_w);
        const float plt0 = (lt0 - pl) * rw;
        const float plt1 = (lt1 - pr) * rw;
        f2 += (fabsf(p0 - plt0) + fabsf(p1 - plt1)) * ppf;

        // centerness BCE (pos only)
        const float cur0 = 0.5f * prop_w * p0 + pl;
        const float cur1 = 0.5f * prop_w * p1 + pr;
        const float inter2 = fminf(cur0, lt0) + fminf(cur1, lt1);
        const float uni2   = cur0 + cur1 + (lt0 + lt1) - inter2;
        const float iou2   = fmaxf(__fdividef(inter2, fmaxf(uni2, EPS)), 0.0f);
        const float bce = fmaxf(lg, 0.0f) - lg * iou2
                          + __logf(1.0f + __expf(-fabsf(lg)));
        f4 += bce * posf;

        // focal on conf (all elements)
        {
            const float xt = conf_t ? x1 : x0;
            const float xo = conf_t ? x0 : x1;
            const float pt = __fdividef(1.0f, 1.0f + __expf(xo - xt)) + 1e-6f;
            const float al = conf_t ? 0.75f : 0.25f;
            const float om = 1.0f - pt;
            f1 += -om * om * al * __logf(pt);
        }
        // focal on prop_conf (all elements)
        {
            const float xt = pconf_t ? y1 : y0;
            const float xo = pconf_t ? y0 : y1;
            const float pt = __fdividef(1.0f, 1.0f + __expf(xo - xt)) + 1e-6f;
            const float al = pconf_t ? 0.75f : 0.25f;
            const float om = 1.0f - pt;
            f3 += -om * om * al * __logf(pt);
        }

        f5 += posf;
        f6 += ppf;
    };

    if (blockIdx.x != gridDim.x - 1) {
        // ---- hot path: no bounds checks, 2-stage software pipeline ----
        float  pc_[2], ct_[2];
        float2 l2_[2], cf2_[2], pl2_[2], pc2_[2];

        #define LOADJ(j, s)                                        \
            {                                                      \
                const int k  = kbase + (j) * TPB;                  \
                const int i2 = bK2 + k * 2;                        \
                pc_[s]  = priors[k];                               \
                l2_[s]  = *(const float2*)(loc   + i2);            \
                cf2_[s] = *(const float2*)(conf  + i2);            \
                pl2_[s] = *(const float2*)(ploc  + i2);            \
                pc2_[s] = *(const float2*)(pconf + i2);            \
                ct_[s]  = center[b * K_ + k];                      \
            }

        LOADJ(0, 0)
        #pragma unroll
        for (int j = 0; j < ITEMS; ++j) {
            const int s = j & 1;
            if (j + 1 < ITEMS) LOADJ(j + 1, 1 - s)
            body(pc_[s], l2_[s].x, l2_[s].y, cf2_[s].x, cf2_[s].y,
                 pl2_[s].x, pl2_[s].y, pc2_[s].x, pc2_[s].y, ct_[s]);
        }
        #undef LOADJ
    } else {
        // ---- tail block: guarded, unpipelined ----
        for (int j = 0; j < ITEMS; ++j) {
            const int k = kbase + j * TPB;
            if (k >= K_) continue;
            const int i2 = bK2 + k * 2;
            const float  c   = priors[k];
            const float2 l2  = *(const float2*)(loc   + i2);
            const float2 cf2 = *(const float2*)(conf  + i2);
            const float2 pl2 = *(const float2*)(ploc  + i2);
            const float2 pc2 = *(const float2*)(pconf + i2);
            const float  lg  = center[b * K_ + k];
            body(c, l2.x, l2.y, cf2.x, cf2.y, pl2.x, pl2.y, pc2.x, pc2.y, lg);
        }
    }

    // ---- block reduction -> per-block partials (no global atomics) ----
    double vals[NACC] = {(double)f0, (double)f1, (double)f2, (double)f3,
                         (double)f4, (double)f5, (double)f6};
    const int wave = t >> 6, lane = t & 63;
    #pragma unroll
    for (int q = 0; q < NACC; ++q) {
        double v = vals[q];
        #pragma unroll
        for (int off = 32; off > 0; off >>= 1)
            v += __shfl_down(v, off, 64);
        if (lane == 0) s_red[wave][q] = v;
    }
    __syncthreads();
    if (t == 0) {
        const int bid = blockIdx.y * gridDim.x + blockIdx.x;
        #pragma unroll
        for (int q = 0; q < NACC; ++q) {
            double s = 0.0;
            #pragma unroll
            for (int w2 = 0; w2 < TPB / 64; ++w2) s += s_red[w2][q];
            partials[(long long)bid * NACC + q] = s;
        }
    }
}

__global__ __launch_bounds__(TPB) void msl_final(
    const double* __restrict__ partials, float* __restrict__ out)
{
    __shared__ double s_red[TPB / 64][NACC];
    double acc[NACC] = {0, 0, 0, 0, 0, 0, 0};
    for (int i = threadIdx.x; i < NBLOCKS; i += TPB) {
        #pragma unroll
        for (int q = 0; q < NACC; ++q)
            acc[q] += partials[(long long)i * NACC + q];
    }
    const int wave = threadIdx.x >> 6, lane = threadIdx.x & 63;
    #pragma unroll
    for (int q = 0; q < NACC; ++q) {
        double v = acc[q];
        #pragma unroll
        for (int off = 32; off > 0; off >>= 1)
            v += __shfl_down(v, off, 64);
        if (lane == 0) s_red[wave][q] = v;
    }
    __syncthreads();
    if (threadIdx.x == 0) {
        double s[NACC];
        #pragma unroll
        for (int q = 0; q < NACC; ++q) {
            double v = 0.0;
            #pragma unroll
            for (int w = 0; w < TPB / 64; ++w) v += s_red[w][q];
            s[q] = v;
        }
        const double Np = fmax(s[5], 1.0);
        const double PN = fmax(s[6], 1.0);
        out[0] = (float)(s[0] / Np);
        out[1] = (float)(s[1] / Np);
        out[2] = (float)(s[2] / PN);
        out[3] = (float)(s[3] / PN);
        out[4] = (float)(s[4] / Np);
    }
}

extern "C" void kernel_launch(void* const* d_in, const int* in_sizes, int n_in,
                              void* d_out, int out_size, void* d_ws, size_t ws_size,
                              hipStream_t stream) {
    const float* loc     = (const float*)d_in[0];
    const float* conf    = (const float*)d_in[1];
    const float* ploc    = (const float*)d_in[2];
    const float* pconf   = (const float*)d_in[3];
    const float* center  = (const float*)d_in[4];
    const float* priors  = (const float*)d_in[5];
    const float* targets = (const float*)d_in[6];
    double* partials = (double*)d_ws;   // 87,808 B

    dim3 grid(NBX, B_);
    msl_main<<<grid, TPB, 0, stream>>>(loc, conf, ploc, pconf, center, priors,
                                       targets, partials);
    msl_final<<<1, TPB, 0, stream>>>(partials, (float*)d_out);
}

// Round 9
// 170.232 us; speedup vs baseline: 1.3659x; 1.3659x over previous
//
#include <hip/hip_runtime.h>
#include <math.h>

#define B_      16
#define K_      200000
#define N_      40
#define TPB     256
#define ITEMS   4
#define TILE    (TPB * ITEMS)                 // 1024 elements per block
#define NBX     ((K_ + TILE - 1) / TILE)      // 196
#define NBLOCKS (NBX * B_)                    // 3136
#define NE      (2 * N_)                      // 80 endpoints
#define NACC    7

// ws layout:
//   [0, PART_BYTES)            : per-block partials (NBLOCKS x 7 floats)
//   [TBL_OFF + b*TBL_STRIDE..) : per-batch tables:
//       float  bp[80]   @ +0     sorted endpoints
//       float4 at4[80]  @ +320   (tl,tr,lab,valid) winner when c == bp[i]
//       float4 gap4[81] @ +1600  (tl,tr,lab,valid) winner for open gap (bp[i-1],bp[i])
#define PART_BYTES  (NBLOCKS * NACC * 4)      // 87,808
#define TBL_OFF     PART_BYTES
#define TBL_STRIDE  3072                      // total ws: 87,808 + 49,152 = 136,960 B

__global__ __launch_bounds__(256) void msl_setup(
    const float* __restrict__ targets, char* __restrict__ ws)
{
    __shared__ float tl0[N_], tr0[N_], lb0[N_], ar0[N_];
    __shared__ float stl[N_], str[N_], slb[N_];
    __shared__ float ep[NE], bp[NE];
    const int b = blockIdx.x, t = threadIdx.x;

    if (t < N_) {
        const float* tg = targets + (b * N_ + t) * 3;
        const float tl = tg[0], tr = tg[1];
        tl0[t] = tl; tr0[t] = tr; lb0[t] = tg[2];
        ar0[t] = (tr - tl) * 256.0f;
    }
    __syncthreads();

    // stable rank-sort segments by area (tie: original index) -> priority order
    if (t < N_) {
        const float an = ar0[t];
        int r = 0;
        #pragma unroll
        for (int m = 0; m < N_; ++m) {
            const float am = ar0[m];
            r += (am < an) || (am == an && m < t);
        }
        stl[r] = tl0[t]; str[r] = tr0[t]; slb[r] = lb0[t];
    }
    if (t < NE) ep[t] = (t < N_) ? tl0[t] : tr0[t - N_];
    __syncthreads();

    // rank-sort endpoints
    if (t < NE) {
        const float v = ep[t];
        int r = 0;
        #pragma unroll
        for (int m = 0; m < NE; ++m) {
            const float vm = ep[m];
            r += (vm < v) || (vm == v && m < t);
        }
        bp[r] = v;
    }
    __syncthreads();

    char* tb = ws + TBL_OFF + b * TBL_STRIDE;

    // point winners: first (priority-order) segment with stl<=v<=str
    if (t < NE) {
        const float v = bp[t];
        int w = N_;
        for (int s = N_ - 1; s >= 0; --s)
            w = (stl[s] <= v && v <= str[s]) ? s : w;
        const bool ok = (w < N_);
        const int si = ok ? w : 0;
        ((float4*)(tb + 320))[t] = ok
            ? make_float4(stl[si], str[si], slb[si], 1.0f)
            : make_float4(0.f, 0.f, 0.f, 0.f);
        ((float*)tb)[t] = v;
    }
    // gap winners: open interval (a, bb) entirely inside [stl, str]
    if (t >= 128 && t < 128 + NE + 1) {
        const int g = t - 128;                 // 0..80
        const float a  = g ? bp[g - 1] : -INFINITY;
        const float bb = (g < NE) ? bp[g] : INFINITY;
        int w = N_;
        for (int s = N_ - 1; s >= 0; --s)
            w = (stl[s] <= a && bb <= str[s]) ? s : w;
        const bool ok = (w < N_);
        const int si = ok ? w : 0;
        ((float4*)(tb + 1600))[g] = ok
            ? make_float4(stl[si], str[si], slb[si], 1.0f)
            : make_float4(0.f, 0.f, 0.f, 0.f);
    }
}

__global__ __launch_bounds__(TPB) void msl_main(
    const float* __restrict__ loc,     // (B,K,2)
    const float* __restrict__ conf,    // (B,K,2)
    const float* __restrict__ ploc,    // (B,K,2)
    const float* __restrict__ pconf,   // (B,K,2)
    const float* __restrict__ center,  // (B,K,1)
    const float* __restrict__ priors,  // (K,1)
    char* __restrict__ ws)
{
    __shared__ float  s_bp[NE];
    __shared__ float4 s_at[NE];
    __shared__ float4 s_gap[NE + 1];
    __shared__ float  s_list[NE];
    __shared__ int    s_bm[2];
    __shared__ double s_red[TPB / 64][NACC];

    const int b = blockIdx.y;
    const int t = threadIdx.x;
    const int kb = blockIdx.x * TILE;

    {
        const char* tb = ws + TBL_OFF + b * TBL_STRIDE;
        if (t < 80)              s_at[t] = ((const float4*)(tb + 320))[t];
        else if (t < 161)        s_gap[t - 80] = ((const float4*)(tb + 1600))[t - 80];
        else if (t < 241)        s_bp[t - 161] = ((const float*)tb)[t - 161];
    }
    __syncthreads();

    // block prologue: winner is piecewise-constant in c; list the breakpoints
    // inside this block's (sorted) prior span — typically 0-2 of the 80.
    if (t == 0) {
        const int kend = (kb + TILE < K_) ? kb + TILE : K_;
        const float cmin = priors[kb];
        const float cmax = priors[kend - 1];
        int base = 0, m = 0;
        for (int i = 0; i < NE; ++i) {
            const float v = s_bp[i];
            base += (v < cmin) ? 1 : 0;
            if (v >= cmin && v <= cmax) s_list[m++] = v;
        }
        s_bm[0] = base; s_bm[1] = m;
    }
    __syncthreads();
    const int base = s_bm[0];
    const int m    = s_bm[1];

    const float EPS = 1.1920928955078125e-7f;  // FLT_EPSILON
    const int bK2 = b * K_ * 2;

    float f0 = 0.f, f1 = 0.f, f2 = 0.f, f3 = 0.f, f4 = 0.f, f5 = 0.f, f6 = 0.f;

    const int kbase = kb + t;
    #pragma unroll
    for (int j = 0; j < ITEMS; ++j) {
        const int k = kbase + j * TPB;
        if (k >= K_) continue;

        const int i2 = bK2 + k * 2;
        const float  c   = priors[k];
        const float2 l2  = *(const float2*)(loc   + i2);
        const float2 cf2 = *(const float2*)(conf  + i2);
        const float2 pl2 = *(const float2*)(ploc  + i2);
        const float2 pc2 = *(const float2*)(pconf + i2);
        const float  lg  = center[b * K_ + k];

        const float pl = l2.x, pr = l2.y;
        const float x0 = cf2.x, x1 = cf2.y;
        const float p0 = pl2.x, p1 = pl2.y;
        const float y0 = pc2.x, y1 = pc2.y;

        // ---- match: pos = #bp <= c over tiny broadcast list ----
        int pos = base; bool eq = false;
        for (int jj = 0; jj < m; ++jj) {
            const float v = s_list[jj];          // wave-uniform broadcast
            pos += (v <= c) ? 1 : 0;
            eq  |= (v == c);
        }
        const float4 sg = eq ? s_at[pos - 1] : s_gap[pos];

        const float tl = sg.x, tr = sg.y;
        const int conf_t = (int)sg.z;            // 0 when unmatched
        const float lt0 = (c - tl) * 256.0f;
        const float lt1 = (tr - c) * 256.0f;

        // ---- iou(loc, loc_t) ----
        const float inter = fminf(pl, lt0) + fminf(pr, lt1);
        const float uni   = pl + pr + (lt0 + lt1) - inter;
        const float iou   = __fdividef(inter, fmaxf(uni, EPS));
        const int pconf_t = (iou < 0.5f) ? 0 : conf_t;

        const float posf = (conf_t > 0) ? 1.0f : 0.0f;
        const float ppf  = (pconf_t > 0) ? 1.0f : 0.0f;

        // GIoU (pos only)
        const float ac   = fmaxf(pl, lt0) + fmaxf(pr, lt1);
        const float giou = iou - __fdividef(ac - uni, fmaxf(ac, EPS));
        f0 += (1.0f - giou) * posf;

        // prop loc L1 (prop-pos only)
        const float prop_w = pl + pr;
        const float rw = __fdividef(1.0f, 0.5f * prop_w);
        const float plt0 = (lt0 - pl) * rw;
        const float plt1 = (lt1 - pr) * rw;
        f2 += (fabsf(p0 - plt0) + fabsf(p1 - plt1)) * ppf;

        // centerness BCE (pos only)
        const float cur0 = 0.5f * prop_w * p0 + pl;
        const float cur1 = 0.5f * prop_w * p1 + pr;
        const float inter2 = fminf(cur0, lt0) + fminf(cur1, lt1);
        const float uni2   = cur0 + cur1 + (lt0 + lt1) - inter2;
        const float iou2   = fmaxf(__fdividef(inter2, fmaxf(uni2, EPS)), 0.0f);
        const float bce = fmaxf(lg, 0.0f) - lg * iou2
                          + __logf(1.0f + __expf(-fabsf(lg)));
        f4 += bce * posf;

        // focal on conf (all elements)
        {
            const float xt = conf_t ? x1 : x0;
            const float xo = conf_t ? x0 : x1;
            const float pt = __fdividef(1.0f, 1.0f + __expf(xo - xt)) + 1e-6f;
            const float al = conf_t ? 0.75f : 0.25f;
            const float om = 1.0f - pt;
            f1 += -om * om * al * __logf(pt);
        }
        // focal on prop_conf (all elements)
        {
            const float xt = pconf_t ? y1 : y0;
            const float xo = pconf_t ? y0 : y1;
            const float pt = __fdividef(1.0f, 1.0f + __expf(xo - xt)) + 1e-6f;
            const float al = pconf_t ? 0.75f : 0.25f;
            const float om = 1.0f - pt;
            f3 += -om * om * al * __logf(pt);
        }

        f5 += posf;
        f6 += ppf;
    }

    // ---- block reduction -> per-block partials (no global atomics) ----
    double vals[NACC] = {(double)f0, (double)f1, (double)f2, (double)f3,
                         (double)f4, (double)f5, (double)f6};
    const int wave = t >> 6, lane = t & 63;
    #pragma unroll
    for (int q = 0; q < NACC; ++q) {
        double v = vals[q];
        #pragma unroll
        for (int off = 32; off > 0; off >>= 1)
            v += __shfl_down(v, off, 64);
        if (lane == 0) s_red[wave][q] = v;
    }
    __syncthreads();
    if (t == 0) {
        float* partials = (float*)ws;
        const int bid = blockIdx.y * gridDim.x + blockIdx.x;
        #pragma unroll
        for (int q = 0; q < NACC; ++q) {
            double s = 0.0;
            #pragma unroll
            for (int w2 = 0; w2 < TPB / 64; ++w2) s += s_red[w2][q];
            partials[(long long)bid * NACC + q] = (float)s;
        }
    }
}

__global__ __launch_bounds__(TPB) void msl_final(
    const float* __restrict__ partials, float* __restrict__ out)
{
    __shared__ double s_red[TPB / 64][NACC];
    double acc[NACC] = {0, 0, 0, 0, 0, 0, 0};
    for (int i = threadIdx.x; i < NBLOCKS; i += TPB) {
        #pragma unroll
        for (int q = 0; q < NACC; ++q)
            acc[q] += (double)partials[(long long)i * NACC + q];
    }
    const int wave = threadIdx.x >> 6, lane = threadIdx.x & 63;
    #pragma unroll
    for (int q = 0; q < NACC; ++q) {
        double v = acc[q];
        #pragma unroll
        for (int off = 32; off > 0; off >>= 1)
            v += __shfl_down(v, off, 64);
        if (lane == 0) s_red[wave][q] = v;
    }
    __syncthreads();
    if (threadIdx.x == 0) {
        double s[NACC];
        #pragma unroll
        for (int q = 0; q < NACC; ++q) {
            double v = 0.0;
            #pragma unroll
            for (int w = 0; w < TPB / 64; ++w) v += s_red[w][q];
            s[q] = v;
        }
        const double Np = fmax(s[5], 1.0);
        const double PN = fmax(s[6], 1.0);
        out[0] = (float)(s[0] / Np);
        out[1] = (float)(s[1] / Np);
        out[2] = (float)(s[2] / PN);
        out[3] = (float)(s[3] / PN);
        out[4] = (float)(s[4] / Np);
    }
}

extern "C" void kernel_launch(void* const* d_in, const int* in_sizes, int n_in,
                              void* d_out, int out_size, void* d_ws, size_t ws_size,
                              hipStream_t stream) {
    const float* loc     = (const float*)d_in[0];
    const float* conf    = (const float*)d_in[1];
    const float* ploc    = (const float*)d_in[2];
    const float* pconf   = (const float*)d_in[3];
    const float* center  = (const float*)d_in[4];
    const float* priors  = (const float*)d_in[5];
    const float* targets = (const float*)d_in[6];
    char* ws = (char*)d_ws;   // uses 87,808 + 16*3072 = 136,960 bytes

    msl_setup<<<B_, 256, 0, stream>>>(targets, ws);
    dim3 grid(NBX, B_);
    msl_main<<<grid, TPB, 0, stream>>>(loc, conf, ploc, pconf, center, priors, ws);
    msl_final<<<1, TPB, 0, stream>>>((const float*)ws, (float*)d_out);
}

// Round 10
// 156.934 us; speedup vs baseline: 1.4817x; 1.0847x over previous
//
#include <hip/hip_runtime.h>
#include <math.h>

#define B_      16
#define K_      200000
#define N_      40
#define TPB     256
#define ITEMS   4
#define TILE    (TPB * ITEMS)                 // 1024 elements per block
#define NBX     ((K_ + TILE - 1) / TILE)      // 196
#define NBLOCKS (NBX * B_)                    // 3136
#define NE      (2 * N_)                      // 80 endpoints
#define NACC    7

// ws layout:
//   [0, PART_BYTES)            : per-block partials (NBLOCKS x 7 floats)
//   [TBL_OFF + b*TBL_STRIDE..) : per-batch tables:
//       float  bp[80]   @ +0     sorted endpoints
//       float4 at4[80]  @ +320   (tl,tr,lab,valid) winner when c == bp[i]
//       float4 gap4[81] @ +1600  (tl,tr,lab,valid) winner for open gap (bp[i-1],bp[i])
#define PART_BYTES  (NBLOCKS * NACC * 4)      // 87,808
#define TBL_OFF     PART_BYTES
#define TBL_STRIDE  3072                      // total ws: 87,808 + 49,152 = 136,960 B

__global__ __launch_bounds__(256) void msl_setup(
    const float* __restrict__ targets, char* __restrict__ ws)
{
    __shared__ float tl0[N_], tr0[N_], lb0[N_], ar0[N_];
    __shared__ float stl[N_], str[N_], slb[N_];
    __shared__ float ep[NE], bp[NE];
    const int b = blockIdx.x, t = threadIdx.x;

    if (t < N_) {
        const float* tg = targets + (b * N_ + t) * 3;
        const float tl = tg[0], tr = tg[1];
        tl0[t] = tl; tr0[t] = tr; lb0[t] = tg[2];
        ar0[t] = (tr - tl) * 256.0f;
    }
    __syncthreads();

    // stable rank-sort segments by area (tie: original index) -> priority order
    if (t < N_) {
        const float an = ar0[t];
        int r = 0;
        #pragma unroll
        for (int m = 0; m < N_; ++m) {
            const float am = ar0[m];
            r += (am < an) || (am == an && m < t);
        }
        stl[r] = tl0[t]; str[r] = tr0[t]; slb[r] = lb0[t];
    }
    if (t < NE) ep[t] = (t < N_) ? tl0[t] : tr0[t - N_];
    __syncthreads();

    // rank-sort endpoints
    if (t < NE) {
        const float v = ep[t];
        int r = 0;
        #pragma unroll
        for (int m = 0; m < NE; ++m) {
            const float vm = ep[m];
            r += (vm < v) || (vm == v && m < t);
        }
        bp[r] = v;
    }
    __syncthreads();

    char* tb = ws + TBL_OFF + b * TBL_STRIDE;

    // point winners: first (priority-order) segment with stl<=v<=str
    if (t < NE) {
        const float v = bp[t];
        int w = N_;
        for (int s = N_ - 1; s >= 0; --s)
            w = (stl[s] <= v && v <= str[s]) ? s : w;
        const bool ok = (w < N_);
        const int si = ok ? w : 0;
        ((float4*)(tb + 320))[t] = ok
            ? make_float4(stl[si], str[si], slb[si], 1.0f)
            : make_float4(0.f, 0.f, 0.f, 0.f);
        ((float*)tb)[t] = v;
    }
    // gap winners: open interval (a, bb) entirely inside [stl, str]
    if (t >= 128 && t < 128 + NE + 1) {
        const int g = t - 128;                 // 0..80
        const float a  = g ? bp[g - 1] : -INFINITY;
        const float bb = (g < NE) ? bp[g] : INFINITY;
        int w = N_;
        for (int s = N_ - 1; s >= 0; --s)
            w = (stl[s] <= a && bb <= str[s]) ? s : w;
        const bool ok = (w < N_);
        const int si = ok ? w : 0;
        ((float4*)(tb + 1600))[g] = ok
            ? make_float4(stl[si], str[si], slb[si], 1.0f)
            : make_float4(0.f, 0.f, 0.f, 0.f);
    }
}

__global__ __launch_bounds__(TPB) void msl_main(
    const float* __restrict__ loc,     // (B,K,2)
    const float* __restrict__ conf,    // (B,K,2)
    const float* __restrict__ ploc,    // (B,K,2)
    const float* __restrict__ pconf,   // (B,K,2)
    const float* __restrict__ center,  // (B,K,1)
    const float* __restrict__ priors,  // (K,1)
    char* __restrict__ ws)
{
    __shared__ float  s_bp[NE];
    __shared__ float4 s_at[NE];
    __shared__ float4 s_gap[NE + 1];
    __shared__ int    s_cnt[4];        // {base_w0, base_w1, end_w0, end_w1}
    __shared__ double s_red[TPB / 64][NACC];

    const int b = blockIdx.y;
    const int t = threadIdx.x;
    const int kb = blockIdx.x * TILE;
    const int kend = (kb + TILE < K_) ? kb + TILE : K_;

    // ---- single-phase prologue: table loads + ballot counts, ONE barrier ----
    {
        const char* tb = ws + TBL_OFF + b * TBL_STRIDE;
        // waves 0-1 (t<128): load bp (pad >=80 with +INF), ballot vs block range
        if (t < 128) {
            const float v = (t < NE) ? ((const float*)tb)[t] : INFINITY;
            if (t < NE) s_bp[t] = v;
            const float cmin = priors[kb];          // uniform -> s_load
            const float cmax = priors[kend - 1];
            const unsigned long long mlo = __ballot(v < cmin);
            const unsigned long long mhi = __ballot(v <= cmax);
            const int wv = t >> 6;                   // 0 or 1
            if ((t & 63) == 0) {
                s_cnt[wv]     = __popcll(mlo);
                s_cnt[2 + wv] = __popcll(mhi);
            }
        } else if (t < 208) {                        // 80 at4 loads
            s_at[t - 128] = ((const float4*)(tb + 320))[t - 128];
        } else {                                     // 48 threads: first gap4 loads
            s_gap[t - 208] = ((const float4*)(tb + 1600))[t - 208];
        }
        if (t < 33)                                  // remaining 33 gap4 loads
            s_gap[48 + t] = ((const float4*)(tb + 1600))[48 + t];
    }
    __syncthreads();

    const int base = s_cnt[0] + s_cnt[1];            // #bp <  cmin
    const int end  = s_cnt[2] + s_cnt[3];            // #bp <= cmax

    const float EPS = 1.1920928955078125e-7f;  // FLT_EPSILON
    const int bK2 = b * K_ * 2;

    float f0 = 0.f, f1 = 0.f, f2 = 0.f, f3 = 0.f, f4 = 0.f, f5 = 0.f, f6 = 0.f;

    const int kbase = kb + t;
    #pragma unroll
    for (int j = 0; j < ITEMS; ++j) {
        const int k = kbase + j * TPB;
        if (k >= K_) continue;

        const int i2 = bK2 + k * 2;
        const float  c   = priors[k];
        const float2 l2  = *(const float2*)(loc   + i2);
        const float2 cf2 = *(const float2*)(conf  + i2);
        const float2 pl2 = *(const float2*)(ploc  + i2);
        const float2 pc2 = *(const float2*)(pconf + i2);
        const float  lg  = center[b * K_ + k];

        const float pl = l2.x, pr = l2.y;
        const float x0 = cf2.x, x1 = cf2.y;
        const float p0 = pl2.x, p1 = pl2.y;
        const float y0 = pc2.x, y1 = pc2.y;

        // ---- match: pos = #bp <= c; in-range bp are contiguous [base,end) ----
        int pos = base; bool eq = false;
        for (int i = base; i < end; ++i) {           // block-uniform bounds
            const float v = s_bp[i];                 // broadcast read
            pos += (v <= c) ? 1 : 0;
            eq  |= (v == c);
        }
        const float4 sg = eq ? s_at[pos - 1] : s_gap[pos];

        const float tl = sg.x, tr = sg.y;
        const int conf_t = (int)sg.z;                // 0 when unmatched
        const float lt0 = (c - tl) * 256.0f;
        const float lt1 = (tr - c) * 256.0f;

        // ---- iou(loc, loc_t) ----
        const float inter = fminf(pl, lt0) + fminf(pr, lt1);
        const float uni   = pl + pr + (lt0 + lt1) - inter;
        const float iou   = __fdividef(inter, fmaxf(uni, EPS));
        const int pconf_t = (iou < 0.5f) ? 0 : conf_t;

        const float posf = (conf_t > 0) ? 1.0f : 0.0f;
        const float ppf  = (pconf_t > 0) ? 1.0f : 0.0f;

        // GIoU (pos only)
        const float ac   = fmaxf(pl, lt0) + fmaxf(pr, lt1);
        const float giou = iou - __fdividef(ac - uni, fmaxf(ac, EPS));
        f0 += (1.0f - giou) * posf;

        // prop loc L1 (prop-pos only)
        const float prop_w = pl + pr;
        const float rw = __fdividef(1.0f, 0.5f * prop_w);
        const float plt0 = (lt0 - pl) * rw;
        const float plt1 = (lt1 - pr) * rw;
        f2 += (fabsf(p0 - plt0) + fabsf(p1 - plt1)) * ppf;

        // centerness BCE (pos only)
        const float cur0 = 0.5f * prop_w * p0 + pl;
        const float cur1 = 0.5f * prop_w * p1 + pr;
        const float inter2 = fminf(cur0, lt0) + fminf(cur1, lt1);
        const float uni2   = cur0 + cur1 + (lt0 + lt1) - inter2;
        const float iou2   = fmaxf(__fdividef(inter2, fmaxf(uni2, EPS)), 0.0f);
        const float bce = fmaxf(lg, 0.0f) - lg * iou2
                          + __logf(1.0f + __expf(-fabsf(lg)));
        f4 += bce * posf;

        // focal on conf (all elements)
        {
            const float xt = conf_t ? x1 : x0;
            const float xo = conf_t ? x0 : x1;
            const float pt = __fdividef(1.0f, 1.0f + __expf(xo - xt)) + 1e-6f;
            const float al = conf_t ? 0.75f : 0.25f;
            const float om = 1.0f - pt;
            f1 += -om * om * al * __logf(pt);
        }
        // focal on prop_conf (all elements)
        {
            const float xt = pconf_t ? y1 : y0;
            const float xo = pconf_t ? y0 : y1;
            const float pt = __fdividef(1.0f, 1.0f + __expf(xo - xt)) + 1e-6f;
            const float al = pconf_t ? 0.75f : 0.25f;
            const float om = 1.0f - pt;
            f3 += -om * om * al * __logf(pt);
        }

        f5 += posf;
        f6 += ppf;
    }

    // ---- block reduction -> per-block partials (no global atomics) ----
    double vals[NACC] = {(double)f0, (double)f1, (double)f2, (double)f3,
                         (double)f4, (double)f5, (double)f6};
    const int wave = t >> 6, lane = t & 63;
    #pragma unroll
    for (int q = 0; q < NACC; ++q) {
        double v = vals[q];
        #pragma unroll
        for (int off = 32; off > 0; off >>= 1)
            v += __shfl_down(v, off, 64);
        if (lane == 0) s_red[wave][q] = v;
    }
    __syncthreads();
    if (t == 0) {
        float* partials = (float*)ws;
        const int bid = blockIdx.y * gridDim.x + blockIdx.x;
        #pragma unroll
        for (int q = 0; q < NACC; ++q) {
            double s = 0.0;
            #pragma unroll
            for (int w2 = 0; w2 < TPB / 64; ++w2) s += s_red[w2][q];
            partials[(long long)bid * NACC + q] = (float)s;
        }
    }
}

__global__ __launch_bounds__(TPB) void msl_final(
    const float* __restrict__ partials, float* __restrict__ out)
{
    __shared__ double s_red[TPB / 64][NACC];
    double acc[NACC] = {0, 0, 0, 0, 0, 0, 0};
    for (int i = threadIdx.x; i < NBLOCKS; i += TPB) {
        #pragma unroll
        for (int q = 0; q < NACC; ++q)
            acc[q] += (double)partials[(long long)i * NACC + q];
    }
    const int wave = threadIdx.x >> 6, lane = threadIdx.x & 63;
    #pragma unroll
    for (int q = 0; q < NACC; ++q) {
        double v = acc[q];
        #pragma unroll
        for (int off = 32; off > 0; off >>= 1)
            v += __shfl_down(v, off, 64);
        if (lane == 0) s_red[wave][q] = v;
    }
    __syncthreads();
    if (threadIdx.x == 0) {
        double s[NACC];
        #pragma unroll
        for (int q = 0; q < NACC; ++q) {
            double v = 0.0;
            #pragma unroll
            for (int w = 0; w < TPB / 64; ++w) v += s_red[w][q];
            s[q] = v;
        }
        const double Np = fmax(s[5], 1.0);
        const double PN = fmax(s[6], 1.0);
        out[0] = (float)(s[0] / Np);
        out[1] = (float)(s[1] / Np);
        out[2] = (float)(s[2] / PN);
        out[3] = (float)(s[3] / PN);
        out[4] = (float)(s[4] / Np);
    }
}

extern "C" void kernel_launch(void* const* d_in, const int* in_sizes, int n_in,
                              void* d_out, int out_size, void* d_ws, size_t ws_size,
                              hipStream_t stream) {
    const float* loc     = (const float*)d_in[0];
    const float* conf    = (const float*)d_in[1];
    const float* ploc    = (const float*)d_in[2];
    const float* pconf   = (const float*)d_in[3];
    const float* center  = (const float*)d_in[4];
    const float* priors  = (const float*)d_in[5];
    const float* targets = (const float*)d_in[6];
    char* ws = (char*)d_ws;   // uses 87,808 + 16*3072 = 136,960 bytes

    msl_setup<<<B_, 256, 0, stream>>>(targets, ws);
    dim3 grid(NBX, B_);
    msl_main<<<grid, TPB, 0, stream>>>(loc, conf, ploc, pconf, center, priors, ws);
    msl_final<<<1, TPB, 0, stream>>>((const float*)ws, (float*)d_out);
}